// Round 1
// 1439.954 us; speedup vs baseline: 1.1574x; 1.1574x over previous
//
#include <hip/hip_runtime.h>

#define SLOPE 0.01f

typedef __attribute__((ext_vector_type(8))) short bf16x8;
typedef __attribute__((ext_vector_type(4))) float f32x4;

__device__ __forceinline__ float lrelu(float v) { return v >= 0.f ? v : SLOPE * v; }

// Truncating fp32 -> (hi, lo) bf16 split: x ~= hi + lo, |x - hi - lo| <= 2^-16 |x|
__device__ __forceinline__ void split_bf16(float x, unsigned short& h, unsigned short& l) {
    unsigned b = __float_as_uint(x);
    unsigned hb = b & 0xFFFF0000u;
    h = (unsigned short)(hb >> 16);
    float r = x - __uint_as_float(hb);
    l = (unsigned short)(__float_as_uint(r) >> 16);
}

// ---------------------------------------------------------------------------
// Weight pre-pass: W[K][128] fp32 -> transposed split Wt_h[c][K], Wt_l[c][K] bf16.
// One block column c per blockIdx.x; blockIdx.y selects which weight.
// ---------------------------------------------------------------------------
__global__ __launch_bounds__(256) void split_w(const float* __restrict__ W_des,
                                               const float* __restrict__ W_in,
                                               const float* __restrict__ W_root,
                                               const float* __restrict__ W0,
                                               const float* __restrict__ W1,
                                               const float* __restrict__ W_out1,
                                               unsigned short* __restrict__ th,
                                               unsigned short* __restrict__ tl) {
    const float* src;
    int K;
    size_t off;
    switch (blockIdx.y) {
        case 0: src = W_des;  K = 768; off = 0;                    break;
        case 1: src = W_in;   K = 128; off = 768 * 128;            break;
        case 2: src = W_root; K = 128; off = 768 * 128 + 16384;    break;
        case 3: src = W0;     K = 128; off = 768 * 128 + 2 * 16384; break;
        case 4: src = W1;     K = 128; off = 768 * 128 + 3 * 16384; break;
        default: src = W_out1; K = 128; off = 768 * 128 + 4 * 16384; break;
    }
    const int c = blockIdx.x;  // 0..127
    unsigned short* dh = th + off + (size_t)c * K;
    unsigned short* dl = tl + off + (size_t)c * K;
    for (int k = threadIdx.x; k < K; k += 256) {
        float v = src[(size_t)k * 128 + c];
        unsigned short h, l;
        split_bf16(v, h, l);
        dh[k] = h;
        dl[k] = l;
    }
}

// ---------------------------------------------------------------------------
// bf16x3 split MFMA GEMM: C[M x 128] = act(sum_seg A_seg[M x K] @ W_seg + bias)
// Tile 128x128, BK=32 fp32. 4 waves, each computes a 64x64 sub-tile via
// 4x4 mfma_f32_16x16x32_bf16 fragments. A split on the fly; W pre-split,
// pre-transposed (Wt[col][k]) so staging is coalesced + conflict-free.
// ---------------------------------------------------------------------------
template <int NSEG, int RELU>
__global__ __launch_bounds__(256, 2) void gemm_mfma(
        const float* __restrict__ A0, const float* __restrict__ A1,
        const float* __restrict__ A2,
        const unsigned short* __restrict__ Wh0, const unsigned short* __restrict__ Wl0,
        const unsigned short* __restrict__ Wh1, const unsigned short* __restrict__ Wl1,
        const unsigned short* __restrict__ Wh2, const unsigned short* __restrict__ Wl2,
        int K0, const float* __restrict__ bias, float* __restrict__ C, int M) {
    __shared__ unsigned short AsH[128][32];   // [row][k] bf16 hi
    __shared__ unsigned short AsL[128][32];   // [row][k] bf16 lo
    __shared__ unsigned short BsH[128][32];   // [col][k] bf16 hi (W^T)
    __shared__ unsigned short BsL[128][32];   // [col][k] bf16 lo

    const int tid = threadIdx.x;
    const int lane = tid & 63;
    const int wv = tid >> 6;          // wave 0..3
    const int wr = (wv >> 1) * 64;    // wave row base in tile
    const int wc = (wv & 1) * 64;     // wave col base in tile
    const int fr = lane & 15;         // fragment row/col
    const int fk = (lane >> 4) * 8;   // fragment k offset (bf16 elems)
    const int m0 = blockIdx.x * 128;

    f32x4 acc[4][4];
#pragma unroll
    for (int i = 0; i < 4; ++i)
#pragma unroll
        for (int j = 0; j < 4; ++j)
#pragma unroll
            for (int r = 0; r < 4; ++r) acc[i][j][r] = 0.f;

    for (int seg = 0; seg < NSEG; ++seg) {
        const float* A = (seg == 0) ? A0 : (seg == 1 ? A1 : A2);
        const unsigned short* Wh = (seg == 0) ? Wh0 : (seg == 1 ? Wh1 : Wh2);
        const unsigned short* Wl = (seg == 0) ? Wl0 : (seg == 1 ? Wl1 : Wl2);
        const int K = (seg == 0) ? K0 : 128;

        for (int k0 = 0; k0 < K; k0 += 32) {
            // ---- stage A tile (128 rows x 32 k): split fp32 -> hi/lo bf16 ----
#pragma unroll
            for (int p = 0; p < 4; ++p) {
                const int f = tid + 256 * p;
                const int r = f >> 3;   // row in tile
                const int q = f & 7;    // k-quad
                int row = m0 + r;
                if (row >= M) row = M - 1;
                const float4 v = *(const float4*)(A + (size_t)row * K + k0 + q * 4);
                unsigned short h0, h1, h2, h3, l0, l1, l2, l3;
                split_bf16(v.x, h0, l0);
                split_bf16(v.y, h1, l1);
                split_bf16(v.z, h2, l2);
                split_bf16(v.w, h3, l3);
                *(ushort4*)&AsH[r][q * 4] = make_ushort4(h0, h1, h2, h3);
                *(ushort4*)&AsL[r][q * 4] = make_ushort4(l0, l1, l2, l3);
            }
            // ---- stage B tile (128 cols x 32 k) from pre-split transposed W ----
#pragma unroll
            for (int p = 0; p < 4; ++p) {
                const int f = tid + 256 * p;
                const int c = f >> 3;
                const int q = f & 7;
                *(ushort4*)&BsH[c][q * 4] = *(const ushort4*)(Wh + (size_t)c * K + k0 + q * 4);
                *(ushort4*)&BsL[c][q * 4] = *(const ushort4*)(Wl + (size_t)c * K + k0 + q * 4);
            }
            __syncthreads();

            bf16x8 ah[4], al[4];
#pragma unroll
            for (int i = 0; i < 4; ++i) {
                ah[i] = *(const bf16x8*)&AsH[wr + i * 16 + fr][fk];
                al[i] = *(const bf16x8*)&AsL[wr + i * 16 + fr][fk];
            }
#pragma unroll
            for (int j = 0; j < 4; ++j) {
                const bf16x8 bh = *(const bf16x8*)&BsH[wc + j * 16 + fr][fk];
                const bf16x8 bl = *(const bf16x8*)&BsL[wc + j * 16 + fr][fk];
#pragma unroll
                for (int i = 0; i < 4; ++i) {
                    acc[i][j] = __builtin_amdgcn_mfma_f32_16x16x32_bf16(ah[i], bh, acc[i][j], 0, 0, 0);
                    acc[i][j] = __builtin_amdgcn_mfma_f32_16x16x32_bf16(ah[i], bl, acc[i][j], 0, 0, 0);
                    acc[i][j] = __builtin_amdgcn_mfma_f32_16x16x32_bf16(al[i], bh, acc[i][j], 0, 0, 0);
                }
            }
            __syncthreads();
        }
    }

    // ---- epilogue: D layout col=lane&15, row=(lane>>4)*4+reg (m89-verified) ----
    const int lr = (lane >> 4) * 4;
    float bv[4];
#pragma unroll
    for (int j = 0; j < 4; ++j) bv[j] = bias[wc + j * 16 + fr];
#pragma unroll
    for (int i = 0; i < 4; ++i) {
#pragma unroll
        for (int r = 0; r < 4; ++r) {
            const int row = m0 + wr + i * 16 + lr + r;
            if (row >= M) continue;
            float* cp = C + (size_t)row * 128 + wc;
#pragma unroll
            for (int j = 0; j < 4; ++j) {
                float v = acc[i][j][r] + bv[j];
                if (RELU) v = lrelu(v);
                cp[j * 16 + fr] = v;
            }
        }
    }
}

// ---------------------------------------------------------------------------
// CSR build: histogram -> 3-stage exclusive scan -> scatter
// Bucket id = r*N + dst  (2N buckets total)
// ---------------------------------------------------------------------------
__global__ __launch_bounds__(256) void hist_kernel(const int* __restrict__ ei,
                                                   const int* __restrict__ et,
                                                   int* __restrict__ cnt, int E, int N) {
    int e = blockIdx.x * 256 + threadIdx.x;
    if (e >= E) return;
    int d = ei[E + e];
    int r = et[e];
    atomicAdd(&cnt[r * N + d], 1);
}

__global__ __launch_bounds__(256) void scan_partial(const int* __restrict__ cnt,
                                                    int* __restrict__ partials, int n) {
    __shared__ int sm[256];
    int base = blockIdx.x * 1024;
    int t = threadIdx.x;
    int s = 0;
#pragma unroll
    for (int i = 0; i < 4; i++) {
        int idx = base + t * 4 + i;
        if (idx < n) s += cnt[idx];
    }
    sm[t] = s;
    __syncthreads();
    for (int off = 128; off; off >>= 1) {
        if (t < off) sm[t] += sm[t + off];
        __syncthreads();
    }
    if (t == 0) partials[blockIdx.x] = sm[0];
}

__global__ __launch_bounds__(64) void scan_top(int* __restrict__ partials, int nb,
                                               int* __restrict__ off, int n, int total) {
    int lane = threadIdx.x;
    int base = 0;
    for (int start = 0; start < nb; start += 64) {
        int idx = start + lane;
        int v = (idx < nb) ? partials[idx] : 0;
        int incl = v;
#pragma unroll
        for (int o = 1; o < 64; o <<= 1) {
            int t = __shfl_up(incl, o);
            if (lane >= o) incl += t;
        }
        if (idx < nb) partials[idx] = base + incl - v;  // exclusive
        base += __shfl(incl, 63);
    }
    if (lane == 0) off[n] = total;
}

__global__ __launch_bounds__(64) void scan_chunk(const int* __restrict__ cnt,
                                                 const int* __restrict__ partials,
                                                 int* __restrict__ off, int n) {
    int lane = threadIdx.x;
    int base = partials[blockIdx.x];
    int cbase = blockIdx.x * 1024;
    for (int i = 0; i < 16; i++) {
        int idx = cbase + i * 64 + lane;
        int v = (idx < n) ? cnt[idx] : 0;
        int incl = v;
#pragma unroll
        for (int o = 1; o < 64; o <<= 1) {
            int t = __shfl_up(incl, o);
            if (lane >= o) incl += t;
        }
        if (idx < n) off[idx] = base + incl - v;
        base += __shfl(incl, 63);
    }
}

__global__ __launch_bounds__(256) void scatter_kernel(const int* __restrict__ ei,
                                                      const int* __restrict__ et,
                                                      const int* __restrict__ off,
                                                      int* __restrict__ cur,
                                                      int* __restrict__ sorted_src,
                                                      int E, int N) {
    int e = blockIdx.x * 256 + threadIdx.x;
    if (e >= E) return;
    int s = ei[e];
    int d = ei[E + e];
    int r = et[e];
    int b = r * N + d;
    int pos = off[b] + atomicAdd(&cur[b], 1);
    sorted_src[pos] = s;
}

// ---------------------------------------------------------------------------
// CSR aggregation: one wave per bucket (r*N+d). lanes hold float2 of D=128.
// Writes mean-normalized agg row (zero if no edges).
// ---------------------------------------------------------------------------
__global__ __launch_bounds__(256) void agg_csr(const int* __restrict__ off,
                                               const int* __restrict__ sorted_src,
                                               const float* __restrict__ X,
                                               float* __restrict__ agg0,
                                               float* __restrict__ agg1,
                                               int N) {
    int w = (int)((blockIdx.x * (unsigned)blockDim.x + threadIdx.x) >> 6);
    if (w >= 2 * N) return;
    int lane = threadIdx.x & 63;
    int start = off[w];
    int end = off[w + 1];
    float2 sum = {0.f, 0.f};
    for (int i = start; i < end; i++) {
        int s = sorted_src[i];
        float2 v = *(const float2*)(X + (size_t)s * 128 + lane * 2);
        sum.x += v.x;
        sum.y += v.y;
    }
    int deg = end - start;
    float inv = (deg > 1) ? (1.f / (float)deg) : 1.f;
    sum.x *= inv;
    sum.y *= inv;
    float* agg = (w < N) ? agg0 : agg1;
    int d = (w < N) ? w : w - N;
    *(float2*)(agg + (size_t)d * 128 + lane * 2) = sum;
}

// ---------------------------------------------------------------------------
// Final projection: out[M x 2] = X[M x 128] @ W[128 x 2] + b. One wave/row.
// ---------------------------------------------------------------------------
__global__ __launch_bounds__(256) void out2_kernel(const float* __restrict__ X,
                                                   const float* __restrict__ W,
                                                   const float* __restrict__ b,
                                                   float* __restrict__ out, int M) {
    const int row = (int)((blockIdx.x * (unsigned)blockDim.x + threadIdx.x) >> 6);
    if (row >= M) return;
    const int lane = threadIdx.x & 63;
    const float* xr = X + (size_t)row * 128;
    float x0 = xr[lane], x1 = xr[lane + 64];
    float s0 = x0 * W[lane * 2 + 0] + x1 * W[(lane + 64) * 2 + 0];
    float s1 = x0 * W[lane * 2 + 1] + x1 * W[(lane + 64) * 2 + 1];
#pragma unroll
    for (int off = 32; off; off >>= 1) {
        s0 += __shfl_down(s0, off);
        s1 += __shfl_down(s1, off);
    }
    if (lane == 0) {
        out[(size_t)row * 2 + 0] = s0 + b[0];
        out[(size_t)row * 2 + 1] = s1 + b[1];
    }
}

extern "C" void kernel_launch(void* const* d_in, const int* in_sizes, int n_in,
                              void* d_out, int out_size, void* d_ws, size_t ws_size,
                              hipStream_t stream) {
    const float* des    = (const float*)d_in[0];
    const int*   ei     = (const int*)d_in[4];
    const int*   et     = (const int*)d_in[5];
    const float* W_des  = (const float*)d_in[6];
    const float* b_des  = (const float*)d_in[7];
    const float* W_in   = (const float*)d_in[8];
    const float* b_in   = (const float*)d_in[9];
    const float* W_rel  = (const float*)d_in[10];
    const float* W_root = (const float*)d_in[11];
    const float* b_rgcn = (const float*)d_in[12];
    const float* W_out1 = (const float*)d_in[13];
    const float* b_out1 = (const float*)d_in[14];
    const float* W_out2 = (const float*)d_in[15];
    const float* b_out2 = (const float*)d_in[16];
    float* out = (float*)d_out;

    const int N = in_sizes[0] / 768;   // 100000
    const int E = in_sizes[5];         // 1600000
    const int TWO_N = 2 * N;
    const float* W0 = W_rel;
    const float* W1 = W_rel + 128 * 128;

    float* ws    = (float*)d_ws;
    float* xA    = ws;                              // N*128 f32
    float* xB    = xA + (size_t)N * 128;            // N*128
    float* agg0  = xB + (size_t)N * 128;            // N*128
    float* agg1  = agg0 + (size_t)N * 128;          // N*128
    int*   cnt   = (int*)(agg1 + (size_t)N * 128);  // 2N
    int*   cur   = cnt + TWO_N;                     // 2N
    int*   off   = cur + TWO_N;                     // 2N+1
    int*   parts = off + TWO_N + 1;                 // ~256
    int*   ssrc  = parts + 256;                     // E

    // pre-split transposed weights (bf16 hi/lo), 16B-aligned
    const size_t OFF_DES  = 0;
    const size_t OFF_IN   = 768 * 128;
    const size_t OFF_ROOT = OFF_IN + 16384;
    const size_t OFF_W0   = OFF_ROOT + 16384;
    const size_t OFF_W1   = OFF_W0 + 16384;
    const size_t OFF_OUT1 = OFF_W1 + 16384;
    const size_t WT_ELEMS = OFF_OUT1 + 16384;  // 1408*128
    uintptr_t wtbase = ((uintptr_t)(ssrc + E) + 15) & ~(uintptr_t)15;
    unsigned short* wth = (unsigned short*)wtbase;
    unsigned short* wtl = wth + WT_ELEMS;

    const int gemmBlocks = (N + 127) / 128;
    const int edgeBlocks = (E + 255) / 256;
    const int aggBlocks  = (TWO_N + 3) / 4;   // 4 waves per 256-thread block
    const int rowBlocks  = (int)(((size_t)N * 64 + 255) / 256);
    const int nChunks    = (TWO_N + 1023) / 1024;

    // ---- weight split (tiny, once per launch) ----
    split_w<<<dim3(128, 6, 1), 256, 0, stream>>>(W_des, W_in, W_root, W0, W1, W_out1, wth, wtl);

    // ---- build CSR (once, reused by both agg passes) ----
    hipMemsetAsync(cnt, 0, (size_t)2 * TWO_N * sizeof(int), stream);  // cnt + cur
    hist_kernel<<<edgeBlocks, 256, 0, stream>>>(ei, et, cnt, E, N);
    scan_partial<<<nChunks, 256, 0, stream>>>(cnt, parts, TWO_N);
    scan_top<<<1, 64, 0, stream>>>(parts, nChunks, off, TWO_N, E);
    scan_chunk<<<nChunks, 64, 0, stream>>>(cnt, parts, off, TWO_N);
    scatter_kernel<<<edgeBlocks, 256, 0, stream>>>(ei, et, off, cur, ssrc, E, N);

    // ---- pipeline (all GEMMs on the matrix pipe via bf16x3 split) ----
    gemm_mfma<1, 1><<<gemmBlocks, 256, 0, stream>>>(
        des, nullptr, nullptr,
        wth + OFF_DES, wtl + OFF_DES, nullptr, nullptr, nullptr, nullptr,
        768, b_des, xA, N);
    gemm_mfma<1, 1><<<gemmBlocks, 256, 0, stream>>>(
        xA, nullptr, nullptr,
        wth + OFF_IN, wtl + OFF_IN, nullptr, nullptr, nullptr, nullptr,
        128, b_in, xB, N);

    agg_csr<<<aggBlocks, 256, 0, stream>>>(off, ssrc, xB, agg0, agg1, N);
    gemm_mfma<3, 0><<<gemmBlocks, 256, 0, stream>>>(
        xB, agg0, agg1,
        wth + OFF_ROOT, wtl + OFF_ROOT, wth + OFF_W0, wtl + OFF_W0, wth + OFF_W1, wtl + OFF_W1,
        128, b_rgcn, xA, N);

    agg_csr<<<aggBlocks, 256, 0, stream>>>(off, ssrc, xA, agg0, agg1, N);
    gemm_mfma<3, 0><<<gemmBlocks, 256, 0, stream>>>(
        xA, agg0, agg1,
        wth + OFF_ROOT, wtl + OFF_ROOT, wth + OFF_W0, wtl + OFF_W0, wth + OFF_W1, wtl + OFF_W1,
        128, b_rgcn, xB, N);

    gemm_mfma<1, 1><<<gemmBlocks, 256, 0, stream>>>(
        xB, nullptr, nullptr,
        wth + OFF_OUT1, wtl + OFF_OUT1, nullptr, nullptr, nullptr, nullptr,
        128, b_out1, xA, N);
    out2_kernel<<<rowBlocks, 256, 0, stream>>>(xA, W_out2, b_out2, out, N);
}